// Round 1
// baseline (321.647 us; speedup 1.0000x reference)
//
#include <hip/hip_runtime.h>
#include <stdint.h>

// Problem constants (B=4, S=4096, D_IN=2048, D_OUT=2048, DELTA_A=0, DELTA_W=0.05)
#define K_DIM   2048
#define N_DIM   2048
#define M_DIM   16384   // B*S
#define DELTA_W 0.05f

#define BM 128
#define BN 128
#define BK 64

typedef __attribute__((ext_vector_type(4))) int i32x4;

// ---------------------------------------------------------------------------
// async global->LDS, 16B per lane. LDS dest must be wave-uniform base + lane*16.
__device__ __forceinline__ void async_copy16(const void* g, void* l) {
    __builtin_amdgcn_global_load_lds(
        (__attribute__((address_space(1))) void*)g,
        (__attribute__((address_space(3))) void*)l,
        16, 0, 0);
}

// 256-thread block sum (4 waves of 64)
__device__ __forceinline__ float block_sum_256(float v, float* sm) {
#pragma unroll
    for (int o = 32; o > 0; o >>= 1) v += __shfl_down(v, o, 64);
    const int lane = threadIdx.x & 63;
    const int w    = threadIdx.x >> 6;
    __syncthreads();              // protect sm reuse across calls
    if (lane == 0) sm[w] = v;
    __syncthreads();
    return sm[0] + sm[1] + sm[2] + sm[3];
}

// ---------------------------------------------------------------------------
// Weight ternarization: one block per output row.
// code[o,d] in {-1,0,1}, alpha[o] = sum(|Wc|*nz)/max(sum(nz),1)
__global__ __launch_bounds__(256) void wquant_kernel(
    const float* __restrict__ W, int8_t* __restrict__ code,
    float* __restrict__ alpha)
{
    __shared__ float sm[4];
    const int row = blockIdx.x;
    const int t   = threadIdx.x;
    const float* Wr = W + (size_t)row * K_DIM;

    float v[8];
    float s = 0.f;
#pragma unroll
    for (int i = 0; i < 8; ++i) { v[i] = Wr[t + i * 256]; s += v[i]; }
    const float mean = block_sum_256(s, sm) * (1.0f / K_DIM);

    float sa = 0.f;
#pragma unroll
    for (int i = 0; i < 8; ++i) sa += fabsf(v[i] - mean);
    const float thr = DELTA_W * (block_sum_256(sa, sm) * (1.0f / K_DIM));

    float ssum = 0.f, scnt = 0.f;
    int8_t q[8];
#pragma unroll
    for (int i = 0; i < 8; ++i) {
        const float c = v[i] - mean;
        const float a = fabsf(c);
        int8_t qv = 0;
        if (a >= thr) qv = (int8_t)((c > 0.f) - (c < 0.f));
        q[i] = qv;
        if (qv != 0) { ssum += a; scnt += 1.0f; }
    }
    const float num = block_sum_256(ssum, sm);
    const float den = block_sum_256(scnt, sm);
    if (t == 0) alpha[row] = num / fmaxf(den, 1.0f);

#pragma unroll
    for (int i = 0; i < 8; ++i)
        code[(size_t)row * K_DIM + t + i * 256] = q[i];
}

// ---------------------------------------------------------------------------
// Activation ternarization: xq = sign(x). DELTA_A==0 -> pure sign.
// float4 load (16B/lane, coalesced), char4 store (4B/lane, coalesced).
__global__ __launch_bounds__(256) void xquant_kernel(
    const float* __restrict__ x, int8_t* __restrict__ xq)
{
    const int i = blockIdx.x * 256 + threadIdx.x;   // over float4 groups
    const float4 f = ((const float4*)x)[i];
    char4 c;
    c.x = (char)((f.x > 0.f) - (f.x < 0.f));
    c.y = (char)((f.y > 0.f) - (f.y < 0.f));
    c.z = (char)((f.z > 0.f) - (f.z < 0.f));
    c.w = (char)((f.w > 0.f) - (f.w < 0.f));
    ((char4*)xq)[i] = c;
}

// ---------------------------------------------------------------------------
// Ternary GEMM: out[m,n] = alpha[n] * (A[m,:] . Bt[n,:]) + bias[n]
// A: [M][K] int8 (sign(x)), Bt: [N][K] int8 (code). m97 structure:
// 128x128 tile, BK=64, 4 waves each computing 4x4 grid of 16x16x64 i8 MFMAs.
// LDS chunk XOR-swizzle: data (row r, 16B-chunk cg) stored at chunk slot
// cs = cg ^ ((r>>1)&3). Staging applies the inverse on the GLOBAL address so
// the LDS destination stays contiguous (global_load_lds requirement).
// Frag ds_read_b128 then hits banks uniformly: 2 lanes/bank-quad = free.
__global__ __launch_bounds__(256) void gemm_kernel(
    const int8_t* __restrict__ A, const int8_t* __restrict__ Bt,
    const float* __restrict__ alpha, const float* __restrict__ bias,
    float* __restrict__ out)
{
    __shared__ __align__(16) int8_t As[BM * BK];   // 8 KiB
    __shared__ __align__(16) int8_t Bs[BN * BK];   // 8 KiB

    const int tid  = threadIdx.x;
    const int lane = tid & 63;
    const int wv   = tid >> 6;        // wave 0..3
    const int wm   = (wv >> 1) * 64;  // wave m-offset in tile
    const int wn   = (wv & 1) * 64;   // wave n-offset in tile

    const int tileM = blockIdx.y * BM;
    const int tileN = blockIdx.x * BN;

    i32x4 acc[4][4] = {};

    // staging coords: slot = issue*256 + tid -> row = slot>>2, chunk slot = tid&3
    const int rs0 = tid >> 2;        // issue-0 row (0..63); issue 1 adds 64
    const int cs  = tid & 3;

    for (int k0 = 0; k0 < K_DIM; k0 += BK) {
        {   // ---- stage A tile (2 issues x 4096B) ----
            int r  = rs0;
            int cg = cs ^ ((r >> 1) & 3);
            async_copy16(A + (size_t)(tileM + r) * K_DIM + k0 + cg * 16,
                         &As[tid * 16]);
            r  = rs0 + 64;
            cg = cs ^ ((r >> 1) & 3);
            async_copy16(A + (size_t)(tileM + r) * K_DIM + k0 + cg * 16,
                         &As[4096 + tid * 16]);
            // ---- stage B tile ----
            r  = rs0;
            cg = cs ^ ((r >> 1) & 3);
            async_copy16(Bt + (size_t)(tileN + r) * K_DIM + k0 + cg * 16,
                         &Bs[tid * 16]);
            r  = rs0 + 64;
            cg = cs ^ ((r >> 1) & 3);
            async_copy16(Bt + (size_t)(tileN + r) * K_DIM + k0 + cg * 16,
                         &Bs[4096 + tid * 16]);
        }
        __syncthreads();   // drains vmcnt before barrier (compiler-inserted)

        // ---- LDS -> fragments ----
        // A-frag layout: A[m = lane&15][k = (lane>>4)*16 + j], j=0..15
        const int fr = lane & 15;
        const int q  = lane >> 4;
        i32x4 af[4], bf[4];
#pragma unroll
        for (int i = 0; i < 4; ++i) {
            const int m   = wm + i * 16 + fr;
            const int csA = q ^ ((m >> 1) & 3);
            af[i] = *(const i32x4*)&As[m * BK + csA * 16];
        }
#pragma unroll
        for (int j = 0; j < 4; ++j) {
            const int n   = wn + j * 16 + fr;
            const int csB = q ^ ((n >> 1) & 3);
            bf[j] = *(const i32x4*)&Bs[n * BK + csB * 16];
        }

        // ---- 16 MFMAs ----
#pragma unroll
        for (int i = 0; i < 4; ++i)
#pragma unroll
            for (int j = 0; j < 4; ++j)
                acc[i][j] = __builtin_amdgcn_mfma_i32_16x16x64_i8(
                    af[i], bf[j], acc[i][j], 0, 0, 0);

        __syncthreads();
    }

    // ---- epilogue: C/D layout col=lane&15, row=(lane>>4)*4+reg ----
    const int cl = lane & 15;
    const int qr = lane >> 4;
#pragma unroll
    for (int j = 0; j < 4; ++j) {
        const int n  = tileN + wn + j * 16 + cl;
        const float al = alpha[n];
        const float bi = bias[n];
#pragma unroll
        for (int i = 0; i < 4; ++i) {
            const int mbase = tileM + wm + i * 16 + qr * 4;
#pragma unroll
            for (int r = 0; r < 4; ++r) {
                out[(size_t)(mbase + r) * N_DIM + n] =
                    al * (float)acc[i][j][r] + bi;
            }
        }
    }
}

// ---------------------------------------------------------------------------
extern "C" void kernel_launch(void* const* d_in, const int* in_sizes, int n_in,
                              void* d_out, int out_size, void* d_ws, size_t ws_size,
                              hipStream_t stream) {
    const float* x = (const float*)d_in[0];   // [4,4096,2048] fp32
    const float* W = (const float*)d_in[1];   // [2048,2048]  fp32
    const float* b = (const float*)d_in[2];   // [2048]       fp32
    float* out = (float*)d_out;               // [4,4096,2048] fp32

    // workspace layout: xq (32 MiB) | wcode (4 MiB) | alpha (8 KiB)
    int8_t* xq    = (int8_t*)d_ws;
    int8_t* wcode = xq + (size_t)M_DIM * K_DIM;
    float*  alpha = (float*)(wcode + (size_t)N_DIM * K_DIM);

    wquant_kernel<<<N_DIM, 256, 0, stream>>>(W, wcode, alpha);
    xquant_kernel<<<(M_DIM * (size_t)K_DIM) / 1024, 256, 0, stream>>>(x, xq);

    dim3 grid(N_DIM / BN, M_DIM / BM);   // (16, 128) = 2048 blocks
    gemm_kernel<<<grid, dim3(256), 0, stream>>>(xq, wcode, alpha, b, out);
}

// Round 4
// 309.336 us; speedup vs baseline: 1.0398x; 1.0398x over previous
//
#include <hip/hip_runtime.h>
#include <stdint.h>

// Problem constants (B=4, S=4096, D_IN=2048, D_OUT=2048, DELTA_A=0, DELTA_W=0.05)
#define K_DIM   2048
#define N_DIM   2048
#define M_DIM   16384   // B*S
#define DELTA_W 0.05f

#define BM 128
#define BN 128
#define BK 128   // R2: was 64. i8 => 2*16KB LDS, 32 MFMAs per barrier pair.

typedef __attribute__((ext_vector_type(4))) int i32x4;

// ---------------------------------------------------------------------------
// async global->LDS, 16B per lane. LDS dest must be wave-uniform base + lane*16.
__device__ __forceinline__ void async_copy16(const void* g, void* l) {
    __builtin_amdgcn_global_load_lds(
        (__attribute__((address_space(1))) void*)g,
        (__attribute__((address_space(3))) void*)l,
        16, 0, 0);
}

// 256-thread block sum (4 waves of 64)
__device__ __forceinline__ float block_sum_256(float v, float* sm) {
#pragma unroll
    for (int o = 32; o > 0; o >>= 1) v += __shfl_down(v, o, 64);
    const int lane = threadIdx.x & 63;
    const int w    = threadIdx.x >> 6;
    __syncthreads();              // protect sm reuse across calls
    if (lane == 0) sm[w] = v;
    __syncthreads();
    return sm[0] + sm[1] + sm[2] + sm[3];
}

// ---------------------------------------------------------------------------
// Fused quantization kernel. Blocks [0, N_DIM): weight ternarization (one
// block per W row). Blocks [N_DIM, N_DIM+8192): activation sign() pass,
// 4 float4-groups per thread. Fusing lets the two independent passes
// co-schedule and removes one launch/drain boundary.
__global__ __launch_bounds__(256) void quant_kernel(
    const float* __restrict__ W, const float* __restrict__ x,
    int8_t* __restrict__ code, float* __restrict__ alpha,
    int8_t* __restrict__ xq)
{
    __shared__ float sm[4];
    const int t = threadIdx.x;

    if (blockIdx.x < N_DIM) {
        // ---- weight ternarization ----
        const int row = blockIdx.x;
        const float* Wr = W + (size_t)row * K_DIM;

        float v[8];
        float s = 0.f;
#pragma unroll
        for (int i = 0; i < 8; ++i) { v[i] = Wr[t + i * 256]; s += v[i]; }
        const float mean = block_sum_256(s, sm) * (1.0f / K_DIM);

        float sa = 0.f;
#pragma unroll
        for (int i = 0; i < 8; ++i) sa += fabsf(v[i] - mean);
        const float thr = DELTA_W * (block_sum_256(sa, sm) * (1.0f / K_DIM));

        float ssum = 0.f, scnt = 0.f;
        int8_t q[8];
#pragma unroll
        for (int i = 0; i < 8; ++i) {
            const float c = v[i] - mean;
            const float a = fabsf(c);
            int8_t qv = 0;
            if (a >= thr) qv = (int8_t)((c > 0.f) - (c < 0.f));
            q[i] = qv;
            if (qv != 0) { ssum += a; scnt += 1.0f; }
        }
        const float num = block_sum_256(ssum, sm);
        const float den = block_sum_256(scnt, sm);
        if (t == 0) alpha[row] = num / fmaxf(den, 1.0f);

#pragma unroll
        for (int i = 0; i < 8; ++i)
            code[(size_t)row * K_DIM + t + i * 256] = q[i];
    } else {
        // ---- activation sign pass: 4 float4 per thread, coalesced ----
        const int blk = blockIdx.x - N_DIM;       // 0..8191
        const int base = blk * 1024 + t;          // float4-group index
        const float4* xin = (const float4*)x;
        char4* xo = (char4*)xq;
#pragma unroll
        for (int i = 0; i < 4; ++i) {
            const float4 f = xin[base + i * 256];
            char4 c;
            c.x = (char)((f.x > 0.f) - (f.x < 0.f));
            c.y = (char)((f.y > 0.f) - (f.y < 0.f));
            c.z = (char)((f.z > 0.f) - (f.z < 0.f));
            c.w = (char)((f.w > 0.f) - (f.w < 0.f));
            xo[base + i * 256] = c;
        }
    }
}

// ---------------------------------------------------------------------------
// Ternary GEMM: out[m,n] = alpha[n] * (A[m,:] . Bt[n,:]) + bias[n]
// A: [M][K] i8 sign(x), Bt: [N][K] i8 code. 128x128 tile, BK=128 (i8 makes
// this 32KB LDS — affordable, unlike bf16's 64KB), 4 waves each computing a
// 4x4 grid of 16x16x64 i8 MFMAs, 2 K-steps per staged tile => 32 MFMAs per
// barrier pair (halves the vmcnt(0)-drain frequency vs BK=64).
//
// LDS swizzle: row stride 128B = 8 chunks of 16B. Data (row r, chunk cg)
// lives at slot cs = cg ^ (r&7). Staging applies the inverse on the GLOBAL
// address so the LDS destination stays lane-contiguous (global_load_lds
// requirement). Fragment reads (16 lanes, consecutive rows, same chunk) then
// spread across all 8 slots with 2 lanes each => 2-way = free (m136).
__global__ __launch_bounds__(256) void gemm_kernel(
    const int8_t* __restrict__ A, const int8_t* __restrict__ Bt,
    const float* __restrict__ alpha, const float* __restrict__ bias,
    float* __restrict__ out)
{
    __shared__ __align__(16) int8_t As[BM * BK];   // 16 KiB
    __shared__ __align__(16) int8_t Bs[BN * BK];   // 16 KiB

    const int tid  = threadIdx.x;
    const int lane = tid & 63;
    const int wv   = tid >> 6;        // wave 0..3
    const int wm   = (wv >> 1) * 64;  // wave m-offset in tile
    const int wn   = (wv & 1) * 64;   // wave n-offset in tile

    const int tileM = blockIdx.y * BM;
    const int tileN = blockIdx.x * BN;

    i32x4 acc[4][4] = {};

    // staging coords: slot = e*256 + tid; row = slot>>3 (8 chunks/row),
    // chunk slot = slot&7; global chunk = slot ^ (row&7).
    const int8_t* aptr[4];
    const int8_t* bptr[4];
#pragma unroll
    for (int e = 0; e < 4; ++e) {
        const int slot = e * 256 + tid;
        const int r    = slot >> 3;
        const int cg   = (slot & 7) ^ (r & 7);
        aptr[e] = A  + (size_t)(tileM + r) * K_DIM + cg * 16;
        bptr[e] = Bt + (size_t)(tileN + r) * K_DIM + cg * 16;
    }

    const int fr = lane & 15;   // fragment row within 16
    const int q  = lane >> 4;   // k-quad 0..3 (16B each)

    for (int k0 = 0; k0 < K_DIM; k0 += BK) {
        // ---- stage A+B tiles: 8 x 4096B issues ----
#pragma unroll
        for (int e = 0; e < 4; ++e) {
            async_copy16(aptr[e] + k0, &As[(e * 256 + tid) * 16]);
            async_copy16(bptr[e] + k0, &Bs[(e * 256 + tid) * 16]);
        }
        __syncthreads();

        // ---- 2 K-steps of 64, 16 MFMAs each ----
#pragma unroll
        for (int kk = 0; kk < 2; ++kk) {
            i32x4 af[4], bf[4];
#pragma unroll
            for (int i = 0; i < 4; ++i) {
                const int m  = wm + i * 16 + fr;
                const int cs = (kk * 4 + q) ^ (m & 7);
                af[i] = *(const i32x4*)&As[m * BK + cs * 16];
            }
#pragma unroll
            for (int j = 0; j < 4; ++j) {
                const int n  = wn + j * 16 + fr;
                const int cs = (kk * 4 + q) ^ (n & 7);
                bf[j] = *(const i32x4*)&Bs[n * BK + cs * 16];
            }
#pragma unroll
            for (int i = 0; i < 4; ++i)
#pragma unroll
                for (int j = 0; j < 4; ++j)
                    acc[i][j] = __builtin_amdgcn_mfma_i32_16x16x64_i8(
                        af[i], bf[j], acc[i][j], 0, 0, 0);
        }
        __syncthreads();
    }

    // ---- epilogue: C/D layout col=lane&15, row=(lane>>4)*4+reg ----
    const int cl = lane & 15;
    const int qr = lane >> 4;
#pragma unroll
    for (int j = 0; j < 4; ++j) {
        const int n  = tileN + wn + j * 16 + cl;
        const float al = alpha[n];
        const float bi = bias[n];
#pragma unroll
        for (int i = 0; i < 4; ++i) {
            const int mbase = tileM + wm + i * 16 + qr * 4;
#pragma unroll
            for (int r = 0; r < 4; ++r) {
                out[(size_t)(mbase + r) * N_DIM + n] =
                    al * (float)acc[i][j][r] + bi;
            }
        }
    }
}

// ---------------------------------------------------------------------------
extern "C" void kernel_launch(void* const* d_in, const int* in_sizes, int n_in,
                              void* d_out, int out_size, void* d_ws, size_t ws_size,
                              hipStream_t stream) {
    const float* x = (const float*)d_in[0];   // [4,4096,2048] fp32
    const float* W = (const float*)d_in[1];   // [2048,2048]  fp32
    const float* b = (const float*)d_in[2];   // [2048]       fp32
    float* out = (float*)d_out;               // [4,4096,2048] fp32

    // workspace layout: xq (32 MiB) | wcode (4 MiB) | alpha (8 KiB)
    int8_t* xq    = (int8_t*)d_ws;
    int8_t* wcode = xq + (size_t)M_DIM * K_DIM;
    float*  alpha = (float*)(wcode + (size_t)N_DIM * K_DIM);

    // 2048 wquant blocks + 8192 xquant blocks in one launch
    quant_kernel<<<N_DIM + 8192, 256, 0, stream>>>(W, x, wcode, alpha, xq);

    dim3 grid(N_DIM / BN, M_DIM / BM);   // (16, 128) = 2048 blocks
    gemm_kernel<<<grid, dim3(256), 0, stream>>>(xq, wcode, alpha, b, out);
}